// Round 1
// baseline (881.584 us; speedup 1.0000x reference)
//
#include <hip/hip_runtime.h>

typedef unsigned short u16;
typedef unsigned int u32;
typedef __attribute__((ext_vector_type(4))) float f32x4;
typedef __attribute__((ext_vector_type(8))) short short8;  // bf16 bits in i16 lanes

constexpr int TT = 2048;   // tokens = B*S
constexpr int HH = 2048;   // hidden
constexpr int FF = 7168;   // ffn
constexpr int RR = 32;     // lora rank
constexpr int KT = 2;      // top-k
constexpr int NA1 = FF + 256;   // 7424: W1/W3 aug N (A1flat/A3flat appended)
constexpr int NA2 = HH + 256;   // 2304: W2 aug N (A2flat appended)

__device__ __forceinline__ float bf2f(u16 v) {
  union { u32 u; float f; } w; w.u = ((u32)v) << 16; return w.f;
}
__device__ __forceinline__ u16 f2bf(float f) {
  union { float f; u32 u; } w; w.f = f;
  u32 u = w.u;
  return (u16)((u + 0x7FFFu + ((u >> 16) & 1u)) >> 16);
}

// global -> LDS direct DMA, 16 bytes/lane. LDS dest must be linear
// (wave-uniform base + lane*16); swizzle lives in the SOURCE address (rule 21).
__device__ __forceinline__ void gload16(const u16* g, u16* l) {
  __builtin_amdgcn_global_load_lds(
      (__attribute__((address_space(1))) void*)g,
      (__attribute__((address_space(3))) void*)l, 16, 0, 0);
}

// ---------------- f32 -> bf16 conversion (grid-stride, float4) ----------------
__global__ __launch_bounds__(256) void cvt_kernel(
    const float* __restrict__ src, u16* __restrict__ dst, int n4) {
  int stride = gridDim.x * 256;
  for (int i = blockIdx.x * 256 + threadIdx.x; i < n4; i += stride) {
    float4 v = ((const float4*)src)[i];
    ushort4 o;
    o.x = f2bf(v.x); o.y = f2bf(v.y); o.z = f2bf(v.z); o.w = f2bf(v.w);
    ((ushort4*)dst)[i] = o;
  }
}

// ---------------- repack B [E, Fdim, R] f32 -> Bm [Fdim, E*R] bf16 ----------------
__global__ __launch_bounds__(256) void repackB_kernel(
    const float* __restrict__ B, u16* __restrict__ Bm, int Fdim) {
  int n = Fdim * 256;
  int stride = gridDim.x * 256;
  for (int i = blockIdx.x * 256 + threadIdx.x; i < n; i += stride) {
    int f = i >> 8, c = i & 255, e = c >> 5, r = c & 31;
    Bm[i] = f2bf(B[((size_t)e * Fdim + f) * RR + r]);
  }
}

// ---------------- gating: logits -> top2 -> weights (f32 exact) ----------------
__global__ __launch_bounds__(64) void gating_kernel(
    const float* __restrict__ X, const float* __restrict__ Wg,
    int* __restrict__ sel, float* __restrict__ rw) {
  int t = blockIdx.x;
  int lane = threadIdx.x;
  const float* x = X + (size_t)t * HH;
  float acc[8] = {};
  for (int h = lane; h < HH; h += 64) {
    float xv = x[h];
#pragma unroll
    for (int e = 0; e < 8; e++) acc[e] += xv * Wg[e * HH + h];
  }
#pragma unroll
  for (int e = 0; e < 8; e++)
    for (int off = 32; off; off >>= 1) acc[e] += __shfl_down(acc[e], off);
  if (lane == 0) {
    int b0 = 0; float l0 = acc[0];
    for (int e = 1; e < 8; e++) if (acc[e] > l0) { l0 = acc[e]; b0 = e; }
    int b1 = -1; float l1 = 0.f;
    for (int e = 0; e < 8; e++) {
      if (e == b0) continue;
      if (b1 < 0 || acc[e] > l1) { l1 = acc[e]; b1 = e; }
    }
    float p = 1.f / (1.f + __expf(l1 - l0));
    sel[t * 2 + 0] = b0; sel[t * 2 + 1] = b1;
    rw[t * 2 + 0] = p;   rw[t * 2 + 1] = 1.f - p;
  }
}

// ---------------- MFMA GEMM: C[M,N] = A[M,K] * Bm[N,K]^T (bf16 in) ----------------
// Staging: global_load_lds width-16, linear LDS dest, pre-swizzled global source.
__global__ __launch_bounds__(256) void gemm_bt(
    const u16* A0, const u16* A1p,
    const u16* B0, const u16* B1p,
    u16* Cb0, u16* Cb1, float* Cf0, float* Cf1,
    int N, int Kd, int out_bf16) {
  const u16* A  = blockIdx.z ? A1p : A0;
  const u16* Bm = blockIdx.z ? B1p : B0;
  u16* Cb       = blockIdx.z ? Cb1 : Cb0;
  float* Cf     = blockIdx.z ? Cf1 : Cf0;

  __shared__ __align__(16) u16 As[128 * 64];
  __shared__ __align__(16) u16 Bs[128 * 64];

  int tid = threadIdx.x;
  int tn = blockIdx.x * 128;
  int tm = blockIdx.y * 128;
  int lane = tid & 63;
  int wave = tid >> 6;
  int wm = (wave >> 1) * 64, wn = (wave & 1) * 64;
  const int r15 = lane & 15, q = lane >> 4;

  f32x4 acc[4][4] = {};

  for (int k0 = 0; k0 < Kd; k0 += 64) {
#pragma unroll
    for (int it = 0; it < 4; it++) {
      int c = it * 256 + tid;
      int row = c >> 3, c8 = c & 7;
      int scol = ((c8 ^ (row & 7)) << 3);
      gload16(A + (size_t)(tm + row) * Kd + (k0 + scol), As + c * 8);
      gload16(Bm + (size_t)(tn + row) * Kd + (k0 + scol), Bs + c * 8);
    }
    __syncthreads();
#pragma unroll
    for (int kk = 0; kk < 2; kk++) {
      short8 af[4], bfr[4];
#pragma unroll
      for (int mi = 0; mi < 4; mi++) {
        int row = wm + mi * 16 + r15;
        int kc = (kk * 4 + q) ^ (row & 7);
        af[mi] = *(const short8*)(As + row * 64 + kc * 8);
      }
#pragma unroll
      for (int ni = 0; ni < 4; ni++) {
        int row = wn + ni * 16 + r15;
        int kc = (kk * 4 + q) ^ (row & 7);
        bfr[ni] = *(const short8*)(Bs + row * 64 + kc * 8);
      }
#pragma unroll
      for (int mi = 0; mi < 4; mi++)
#pragma unroll
        for (int ni = 0; ni < 4; ni++)
          acc[mi][ni] = __builtin_amdgcn_mfma_f32_16x16x32_bf16(af[mi], bfr[ni], acc[mi][ni], 0, 0, 0);
    }
    __syncthreads();
  }
#pragma unroll
  for (int mi = 0; mi < 4; mi++)
#pragma unroll
    for (int ni = 0; ni < 4; ni++)
#pragma unroll
      for (int i = 0; i < 4; i++) {
        int r = tm + wm + mi * 16 + q * 4 + i;
        int cc = tn + wn + ni * 16 + r15;
        float v = acc[mi][ni][i];
        if (out_bf16) Cb[(size_t)r * N + cc] = f2bf(v);
        else          Cf[(size_t)r * N + cc] = v;
      }
}

// ---------------- mask/expand: a1_all/a3_all (Y-aug cols) -> zero-padded ahat ----------------
__global__ __launch_bounds__(256) void mask13_kernel(
    const u16* __restrict__ Y1, const u16* __restrict__ Y3,
    const int* __restrict__ sel, u16* __restrict__ ah1, u16* __restrict__ ah3) {
  int tk = blockIdx.x;
  int t = tk >> 1;
  int e = sel[tk] & 7;
  int c = threadIdx.x;
  bool in = (c >> 5) == e;
  ah1[(size_t)tk * 256 + c] = in ? Y1[(size_t)t * NA1 + FF + c] : (u16)0;
  ah3[(size_t)tk * 256 + c] = in ? Y3[(size_t)t * NA1 + FF + c] : (u16)0;
}

__global__ __launch_bounds__(256) void mask2_kernel(
    const u16* __restrict__ down_aug, const int* __restrict__ sel,
    u16* __restrict__ ah2) {
  int tk = blockIdx.x;
  int t = tk >> 1, k = tk & 1;
  int e = sel[tk] & 7;
  int c = threadIdx.x;
  ah2[(size_t)tk * 256 + c] =
      ((c >> 5) == e) ? down_aug[((size_t)k * TT + t) * NA2 + HH + c] : (u16)0;
}

// ---------------- fused lora1/lora3 GEMM + add-base + silu -> X2 ----------------
// C1 = ah1[4096,256] * Bm1[7168,256]^T ; C3 likewise; then
// X2[k,t,f] = silu(Y1[t,f]+C1[tk,f]) * (Y3[t,f]+C3[tk,f]),  tk = t*2+k.
// B-tiles staged in LDS via global_load_lds (pre-swizzled source);
// A-fragments read direct from global (L2-resident, 2 MB).
__global__ __launch_bounds__(256) void lora_silu_kernel(
    const u16* __restrict__ ah1, const u16* __restrict__ ah3,
    const u16* __restrict__ Bm1, const u16* __restrict__ Bm3,
    const u16* __restrict__ Y1, const u16* __restrict__ Y3,
    u16* __restrict__ X2) {
  __shared__ __align__(16) u16 Bs1[128 * 64];
  __shared__ __align__(16) u16 Bs3[128 * 64];
  int tid = threadIdx.x;
  int tn = blockIdx.x * 128;   // f tile
  int tm = blockIdx.y * 128;   // slot (tk) tile
  int lane = tid & 63, wave = tid >> 6;
  int wm = (wave >> 1) * 64, wn = (wave & 1) * 64;
  const int r15 = lane & 15, q = lane >> 4;

  f32x4 acc1[4][4] = {}, acc3[4][4] = {};

  for (int k0 = 0; k0 < 256; k0 += 64) {
#pragma unroll
    for (int it = 0; it < 4; it++) {
      int c = it * 256 + tid;
      int row = c >> 3, c8 = c & 7;
      int scol = ((c8 ^ (row & 7)) << 3);
      gload16(Bm1 + (size_t)(tn + row) * 256 + (k0 + scol), Bs1 + c * 8);
      gload16(Bm3 + (size_t)(tn + row) * 256 + (k0 + scol), Bs3 + c * 8);
    }
    __syncthreads();
#pragma unroll
    for (int kk = 0; kk < 2; kk++) {
      short8 a1f[4], a3f[4], b1f[4], b3f[4];
#pragma unroll
      for (int mi = 0; mi < 4; mi++) {
        int row = tm + wm + mi * 16 + r15;
        size_t o = (size_t)row * 256 + k0 + (kk * 4 + q) * 8;
        a1f[mi] = *(const short8*)(ah1 + o);
        a3f[mi] = *(const short8*)(ah3 + o);
      }
#pragma unroll
      for (int ni = 0; ni < 4; ni++) {
        int row = wn + ni * 16 + r15;
        int kc = (kk * 4 + q) ^ (row & 7);
        b1f[ni] = *(const short8*)(Bs1 + row * 64 + kc * 8);
        b3f[ni] = *(const short8*)(Bs3 + row * 64 + kc * 8);
      }
#pragma unroll
      for (int mi = 0; mi < 4; mi++)
#pragma unroll
        for (int ni = 0; ni < 4; ni++) {
          acc1[mi][ni] = __builtin_amdgcn_mfma_f32_16x16x32_bf16(a1f[mi], b1f[ni], acc1[mi][ni], 0, 0, 0);
          acc3[mi][ni] = __builtin_amdgcn_mfma_f32_16x16x32_bf16(a3f[mi], b3f[ni], acc3[mi][ni], 0, 0, 0);
        }
    }
    __syncthreads();
  }
#pragma unroll
  for (int mi = 0; mi < 4; mi++)
#pragma unroll
    for (int ni = 0; ni < 4; ni++)
#pragma unroll
      for (int i = 0; i < 4; i++) {
        int row = tm + wm + mi * 16 + q * 4 + i;   // tk slot
        int f = tn + wn + ni * 16 + r15;
        int t = row >> 1, k = row & 1;
        float x1 = bf2f(Y1[(size_t)t * NA1 + f]) + acc1[mi][ni][i];
        float x3 = bf2f(Y3[(size_t)t * NA1 + f]) + acc3[mi][ni][i];
        float sig = 1.f / (1.f + __expf(-x1));
        X2[((size_t)k * TT + t) * FF + f] = f2bf(x1 * sig * x3);
      }
}

// ---------------- out = sum_k rw_k * (down_k + lora2_k)  (f32 out, vectorized) ----------------
__global__ __launch_bounds__(256) void final_kernel(
    const u16* __restrict__ down_aug, const float* __restrict__ L2b,
    const float* __restrict__ rw, float* __restrict__ out) {
  int t = blockIdx.x;
  float r0 = rw[t * 2], r1 = rw[t * 2 + 1];
  int h = threadIdx.x * 8;   // 256 threads * 8 = 2048 = HH exactly
  short8 d0v = *(const short8*)(down_aug + (size_t)t * NA2 + h);
  short8 d1v = *(const short8*)(down_aug + ((size_t)TT + t) * NA2 + h);
  const float* l0p = L2b + (size_t)(t * 2) * HH + h;
  const float* l1p = L2b + (size_t)(t * 2 + 1) * HH + h;
  f32x4 l0a = *(const f32x4*)(l0p),     l0b = *(const f32x4*)(l0p + 4);
  f32x4 l1a = *(const f32x4*)(l1p),     l1b = *(const f32x4*)(l1p + 4);
  f32x4 oa, ob;
#pragma unroll
  for (int j = 0; j < 4; j++) {
    oa[j] = r0 * (bf2f((u16)d0v[j])     + l0a[j]) + r1 * (bf2f((u16)d1v[j])     + l1a[j]);
    ob[j] = r0 * (bf2f((u16)d0v[j + 4]) + l0b[j]) + r1 * (bf2f((u16)d1v[j + 4]) + l1b[j]);
  }
  float* op = out + (size_t)t * HH + h;
  *(f32x4*)(op)     = oa;
  *(f32x4*)(op + 4) = ob;
}

extern "C" void kernel_launch(void* const* d_in, const int* in_sizes, int n_in,
                              void* d_out, int out_size, void* d_ws, size_t ws_size,
                              hipStream_t stream) {
  if (n_in < 11) return;
  const float* X  = (const float*)d_in[0];
  const float* Wg = (const float*)d_in[1];
  const float* W1 = (const float*)d_in[2];
  const float* W2 = (const float*)d_in[3];
  const float* W3 = (const float*)d_in[4];
  const float* A1 = (const float*)d_in[5];
  const float* B1 = (const float*)d_in[6];
  const float* A2 = (const float*)d_in[7];
  const float* B2 = (const float*)d_in[8];
  const float* A3 = (const float*)d_in[9];
  const float* B3 = (const float*)d_in[10];
  float* out = (float*)d_out;

  char* ws = (char*)d_ws;
  size_t off = 0;
  auto take = [&](size_t bytes) -> void* {
    void* p = ws + off;
    off += (bytes + 255) & ~(size_t)255;
    return p;
  };
  u16*   Xb     = (u16*)take((size_t)TT * HH * 2);
  u16*   W1augb = (u16*)take((size_t)NA1 * HH * 2);   // rows: W1 | A1flat
  u16*   W3augb = (u16*)take((size_t)NA1 * HH * 2);   // rows: W3 | A3flat
  u16*   W2augb = (u16*)take((size_t)NA2 * FF * 2);   // rows: W2 | A2flat
  u16*   Bm1    = (u16*)take((size_t)FF * 256 * 2);
  u16*   Bm3    = (u16*)take((size_t)FF * 256 * 2);
  u16*   Bm2    = (u16*)take((size_t)HH * 256 * 2);
  u16*   Y1aug  = (u16*)take((size_t)TT * NA1 * 2);
  u16*   Y3aug  = (u16*)take((size_t)TT * NA1 * 2);
  u16*   ah1    = (u16*)take((size_t)TT * KT * 256 * 2);
  u16*   ah3    = (u16*)take((size_t)TT * KT * 256 * 2);
  u16*   ah2    = (u16*)take((size_t)TT * KT * 256 * 2);
  u16*   X2     = (u16*)take((size_t)KT * TT * FF * 2);
  int*   sel    = (int*)take((size_t)TT * KT * 4);
  float* rw     = (float*)take((size_t)TT * KT * 4);
  if (off > ws_size) return;
  // Aliases into regions that are dead by the time these are written:
  // down_aug (2*2048*2304*2 = 18.9 MB) overlays W1augb (dead after GEMM13).
  // L2b (4096*2048*4 = 33.6 MB) overlays W3augb + start of W2augb (both dead after down GEMM).
  u16*   down_aug = W1augb;
  float* L2b      = (float*)W3augb;

  // --- precompute: bf16 casts + repacks (weights are reused many times) ---
  cvt_kernel<<<1024, 256, 0, stream>>>(X,  Xb, TT * HH / 4);
  cvt_kernel<<<1024, 256, 0, stream>>>(W1, W1augb, FF * HH / 4);
  cvt_kernel<<<1024, 256, 0, stream>>>(A1, W1augb + (size_t)FF * HH, 256 * HH / 4);
  cvt_kernel<<<1024, 256, 0, stream>>>(W3, W3augb, FF * HH / 4);
  cvt_kernel<<<1024, 256, 0, stream>>>(A3, W3augb + (size_t)FF * HH, 256 * HH / 4);
  cvt_kernel<<<1024, 256, 0, stream>>>(W2, W2augb, HH * FF / 4);
  cvt_kernel<<<1024, 256, 0, stream>>>(A2, W2augb + (size_t)HH * FF, 256 * FF / 4);
  repackB_kernel<<<1024, 256, 0, stream>>>(B1, Bm1, FF);
  repackB_kernel<<<1024, 256, 0, stream>>>(B3, Bm3, FF);
  repackB_kernel<<<1024, 256, 0, stream>>>(B2, Bm2, HH);
  gating_kernel<<<TT, 64, 0, stream>>>(X, Wg, sel, rw);

  // --- Y1aug/Y3aug = Xb @ [W1|A1flat]^T, [W3|A3flat]^T  (a1_all/a3_all free in cols F..) ---
  gemm_bt<<<dim3(NA1 / 128, TT / 128, 2), 256, 0, stream>>>(
      Xb, Xb, W1augb, W3augb, Y1aug, Y3aug, nullptr, nullptr, NA1, HH, 1);
  mask13_kernel<<<TT * KT, 256, 0, stream>>>(Y1aug, Y3aug, sel, ah1, ah3);
  // --- X2 = silu(Y1 + ah1@Bm1^T) * (Y3 + ah3@Bm3^T) ---
  lora_silu_kernel<<<dim3(FF / 128, TT * KT / 128), 256, 0, stream>>>(
      ah1, ah3, Bm1, Bm3, Y1aug, Y3aug, X2);
  // --- down_aug = X2[k] @ [W2|A2flat]^T  (a2_all free in cols H..) ---
  gemm_bt<<<dim3(NA2 / 128, TT / 128, 2), 256, 0, stream>>>(
      X2, X2 + (size_t)TT * FF, W2augb, W2augb,
      down_aug, down_aug + (size_t)TT * NA2, nullptr, nullptr, NA2, FF, 1);
  mask2_kernel<<<TT * KT, 256, 0, stream>>>(down_aug, sel, ah2);
  // --- L2b = ah2 @ Bm2^T ---
  gemm_bt<<<dim3(HH / 128, TT * KT / 128, 1), 256, 0, stream>>>(
      ah2, ah2, Bm2, Bm2, nullptr, nullptr, L2b, L2b, HH, 256, 0);
  final_kernel<<<TT, 256, 0, stream>>>(down_aug, L2b, rw, out);
}

// Round 2
// 704.234 us; speedup vs baseline: 1.2518x; 1.2518x over previous
//
#include <hip/hip_runtime.h>

typedef unsigned short u16;
typedef unsigned int u32;
typedef __attribute__((ext_vector_type(4))) float f32x4;
typedef __attribute__((ext_vector_type(8))) short short8;  // bf16 bits in i16 lanes

constexpr int TT = 2048;   // tokens = B*S
constexpr int HH = 2048;   // hidden
constexpr int FF = 7168;   // ffn
constexpr int RR = 32;     // lora rank
constexpr int KT = 2;      // top-k
constexpr int NA1 = FF + 256;   // 7424: W1/W3 aug N (A1flat/A3flat appended)
constexpr int NA2 = HH + 256;   // 2304: W2 aug N (A2flat appended)

__device__ __forceinline__ float bf2f(u16 v) {
  union { u32 u; float f; } w; w.u = ((u32)v) << 16; return w.f;
}
__device__ __forceinline__ u16 f2bf(float f) {
  union { float f; u32 u; } w; w.f = f;
  u32 u = w.u;
  return (u16)((u + 0x7FFFu + ((u >> 16) & 1u)) >> 16);
}

// global -> LDS direct DMA, 16 bytes/lane. LDS dest must be linear
// (wave-uniform base + lane*16); swizzle lives in the SOURCE address (rule 21).
__device__ __forceinline__ void gload16(const u16* g, u16* l) {
  __builtin_amdgcn_global_load_lds(
      (__attribute__((address_space(1))) void*)g,
      (__attribute__((address_space(3))) void*)l, 16, 0, 0);
}

// raw barrier (no vmcnt drain) + explicit waits — 8-phase schedule plumbing
__device__ __forceinline__ void bar_mem() { asm volatile("s_barrier" ::: "memory"); }
__device__ __forceinline__ void lgk0() { asm volatile("s_waitcnt lgkmcnt(0)" ::: "memory"); }
template <int N>
__device__ __forceinline__ void vmw() { asm volatile("s_waitcnt vmcnt(%0)" :: "n"(N) : "memory"); }

// ---------------- f32 -> bf16 conversion (grid-stride, float4) ----------------
__global__ __launch_bounds__(256) void cvt_kernel(
    const float* __restrict__ src, u16* __restrict__ dst, int n4) {
  int stride = gridDim.x * 256;
  for (int i = blockIdx.x * 256 + threadIdx.x; i < n4; i += stride) {
    float4 v = ((const float4*)src)[i];
    ushort4 o;
    o.x = f2bf(v.x); o.y = f2bf(v.y); o.z = f2bf(v.z); o.w = f2bf(v.w);
    ((ushort4*)dst)[i] = o;
  }
}

// ---------------- repack B [E, Fdim, R] f32 -> Bm [Fdim, E*R] bf16 ----------------
__global__ __launch_bounds__(256) void repackB_kernel(
    const float* __restrict__ B, u16* __restrict__ Bm, int Fdim) {
  int n = Fdim * 256;
  int stride = gridDim.x * 256;
  for (int i = blockIdx.x * 256 + threadIdx.x; i < n; i += stride) {
    int f = i >> 8, c = i & 255, e = c >> 5, r = c & 31;
    Bm[i] = f2bf(B[((size_t)e * Fdim + f) * RR + r]);
  }
}

// ---------------- gating: logits -> top2 -> weights (f32 exact) ----------------
__global__ __launch_bounds__(64) void gating_kernel(
    const float* __restrict__ X, const float* __restrict__ Wg,
    int* __restrict__ sel, float* __restrict__ rw) {
  int t = blockIdx.x;
  int lane = threadIdx.x;
  const float* x = X + (size_t)t * HH;
  float acc[8] = {};
  for (int h = lane; h < HH; h += 64) {
    float xv = x[h];
#pragma unroll
    for (int e = 0; e < 8; e++) acc[e] += xv * Wg[e * HH + h];
  }
#pragma unroll
  for (int e = 0; e < 8; e++)
    for (int off = 32; off; off >>= 1) acc[e] += __shfl_down(acc[e], off);
  if (lane == 0) {
    int b0 = 0; float l0 = acc[0];
    for (int e = 1; e < 8; e++) if (acc[e] > l0) { l0 = acc[e]; b0 = e; }
    int b1 = -1; float l1 = 0.f;
    for (int e = 0; e < 8; e++) {
      if (e == b0) continue;
      if (b1 < 0 || acc[e] > l1) { l1 = acc[e]; b1 = e; }
    }
    float p = 1.f / (1.f + __expf(l1 - l0));
    sel[t * 2 + 0] = b0; sel[t * 2 + 1] = b1;
    rw[t * 2 + 0] = p;   rw[t * 2 + 1] = 1.f - p;
  }
}

// ================= 256x256 8-phase MFMA GEMM (T1+T2+T3+T4+T5) =================
// C[M,N] = A[M,K] * Bm[N,K]^T, bf16 in/out. M=2048 multiple of 256, N mult of 256,
// K mult of 128. 8 waves (2M x 4N), per-wave 128x64 output. LDS 128 KiB:
// double-buffered A/B 256x64 tiles, XOR-swizzled (pre-swizzled gload source).
// Half-tile staging map (region last-read -> stage phase, all verified):
//   P1: t1.A_lo  P2: t1.A_hi  P3: t2.B_lo  P4: t2.B_hi [vmcnt(4)]
//   P5: t2.A_lo  P6: t2.A_hi  P7: t3.B_lo  P8: t3.B_hi [vmcnt(4)]
__device__ __forceinline__ void stageH(const u16* g, int stride, int row0, int k0,
                                       u16* l) {
  const int tid = threadIdx.x;
#pragma unroll
  for (int j = 0; j < 2; ++j) {
    int c = (j << 9) + tid;            // 0..1023 -> 128 rows x 64 cols
    int row = c >> 3, c8 = c & 7;
    int sc = ((c8 ^ (row & 7)) << 3);  // pre-swizzled source column
    gload16(g + (size_t)(row0 + row) * stride + (k0 + sc), l + c * 8);
  }
}

#define RD_A(buf, mo)                                                         \
  _Pragma("unroll") for (int j = 0; j < 4; ++j)                               \
  _Pragma("unroll") for (int ks = 0; ks < 2; ++ks) {                          \
    int row = wmw + (mo + j) * 16 + r15;                                      \
    a[j * 2 + ks] = *(const short8*)((buf) + row * 64 +                       \
                                     (((ks * 4 + q) ^ (row & 7)) << 3));      \
  }
#define RD_B(buf, reg, no)                                                    \
  _Pragma("unroll") for (int n = 0; n < 2; ++n)                               \
  _Pragma("unroll") for (int ks = 0; ks < 2; ++ks) {                          \
    int row = wnw + (no + n) * 16 + r15;                                      \
    reg[n * 2 + ks] = *(const short8*)((buf) + row * 64 +                     \
                                       (((ks * 4 + q) ^ (row & 7)) << 3));    \
  }
#define MMQ(mo, reg, no)                                                      \
  _Pragma("unroll") for (int m = 0; m < 4; ++m)                               \
  _Pragma("unroll") for (int n = 0; n < 2; ++n)                               \
  _Pragma("unroll") for (int ks = 0; ks < 2; ++ks)                            \
    acc[mo + m][no + n] = __builtin_amdgcn_mfma_f32_16x16x32_bf16(            \
        a[m * 2 + ks], reg[n * 2 + ks], acc[mo + m][no + n], 0, 0, 0);

__global__ __launch_bounds__(512, 2) void gemm256(
    const u16* A0, const u16* A1p, const u16* B0, const u16* B1p,
    u16* Cb0, u16* Cb1, int N, int Kd) {
  const u16* A  = blockIdx.z ? A1p : A0;
  const u16* Bm = blockIdx.z ? B1p : B0;
  u16* Cb       = blockIdx.z ? Cb1 : Cb0;

  __shared__ __align__(16) u16 S[65536];  // 128 KiB: A0 | B0 | A1 | B1 (256x64 each)
  u16* A0b = S;
  u16* B0b = S + 16384;
  u16* A1b = S + 32768;
  u16* B1b = S + 49152;

  // XCD-aware bijective swizzle (nwg % 8 == 0 for both call sites), N-chunked.
  const int gx = gridDim.x, gy = gridDim.y;
  const int nwg = gx * gy;
  const int orig = blockIdx.y * gx + blockIdx.x;
  const int wg = (orig & 7) * (nwg >> 3) + (orig >> 3);
  const int tn = (wg / gy) * 256;
  const int tm = (wg % gy) * 256;

  const int tid = threadIdx.x;
  const int lane = tid & 63, wave = tid >> 6;
  const int wmw = (wave >> 2) * 128;   // wave M offset (2 groups)
  const int wnw = (wave & 3) * 64;     // wave N offset (4 groups)
  const int r15 = lane & 15, q = lane >> 4;

  f32x4 acc[8][4] = {};
  short8 a[8], bl[4], bh[4];

  const int nIter = Kd >> 7;   // pairs of 64-wide K-tiles

  // prologue: tile0 complete + tile1's B halves; leave 2 half-tiles in flight
  stageH(A,  Kd, tm,       0,  A0b);
  stageH(A,  Kd, tm + 128, 0,  A0b + 8192);
  stageH(Bm, Kd, tn,       0,  B0b);
  stageH(Bm, Kd, tn + 128, 0,  B0b + 8192);
  stageH(Bm, Kd, tn,       64, B1b);
  stageH(Bm, Kd, tn + 128, 64, B1b + 8192);
  vmw<4>();
  bar_mem();

  for (int it = 0; it < nIter; ++it) {
    const bool st = (it + 1 < nIter);
    const int k1 = (2 * it + 1) << 6;
    const int k2 = (2 * it + 2) << 6;
    const int k3 = (2 * it + 3) << 6;

    // ---- K-tile t0 (buf0) ----
    // P1: Q1 (M-lo x N-lo)
    RD_A(A0b, 0) RD_B(B0b, bl, 0)
    stageH(A, Kd, tm, k1, A1b);
    bar_mem(); lgk0();
    __builtin_amdgcn_s_setprio(1); MMQ(0, bl, 0) __builtin_amdgcn_s_setprio(0);
    lgk0(); bar_mem();
    // P2: Q2 (M-lo x N-hi)
    RD_B(B0b, bh, 2)
    stageH(A, Kd, tm + 128, k1, A1b + 8192);
    bar_mem(); lgk0();
    __builtin_amdgcn_s_setprio(1); MMQ(0, bh, 2) __builtin_amdgcn_s_setprio(0);
    lgk0(); bar_mem();
    // P3: Q3 (M-hi x N-hi)
    RD_A(A0b, 4)
    if (st) stageH(Bm, Kd, tn, k2, B0b);
    bar_mem(); lgk0();
    __builtin_amdgcn_s_setprio(1); MMQ(4, bh, 2) __builtin_amdgcn_s_setprio(0);
    lgk0(); bar_mem();
    // P4: Q4 (M-hi x N-lo); K-tile boundary: counted vmcnt, never 0 mid-loop
    if (st) stageH(Bm, Kd, tn + 128, k2, B0b + 8192);
    bar_mem();
    __builtin_amdgcn_s_setprio(1); MMQ(4, bl, 0) __builtin_amdgcn_s_setprio(0);
    if (st) vmw<4>(); else vmw<0>();
    lgk0(); bar_mem();

    // ---- K-tile t1 (buf1) ----
    // P5
    RD_A(A1b, 0) RD_B(B1b, bl, 0)
    if (st) stageH(A, Kd, tm, k2, A0b);
    bar_mem(); lgk0();
    __builtin_amdgcn_s_setprio(1); MMQ(0, bl, 0) __builtin_amdgcn_s_setprio(0);
    lgk0(); bar_mem();
    // P6
    RD_B(B1b, bh, 2)
    if (st) stageH(A, Kd, tm + 128, k2, A0b + 8192);
    bar_mem(); lgk0();
    __builtin_amdgcn_s_setprio(1); MMQ(0, bh, 2) __builtin_amdgcn_s_setprio(0);
    lgk0(); bar_mem();
    // P7
    RD_A(A1b, 4)
    if (st) stageH(Bm, Kd, tn, k3, B1b);
    bar_mem(); lgk0();
    __builtin_amdgcn_s_setprio(1); MMQ(4, bh, 2) __builtin_amdgcn_s_setprio(0);
    lgk0(); bar_mem();
    // P8: K-tile boundary
    if (st) stageH(Bm, Kd, tn + 128, k3, B1b + 8192);
    bar_mem();
    __builtin_amdgcn_s_setprio(1); MMQ(4, bl, 0) __builtin_amdgcn_s_setprio(0);
    if (st) vmw<4>();
    lgk0(); bar_mem();
  }

#pragma unroll
  for (int m = 0; m < 8; ++m)
#pragma unroll
    for (int n = 0; n < 4; ++n)
#pragma unroll
      for (int i = 0; i < 4; ++i) {
        int r = tm + wmw + m * 16 + q * 4 + i;
        int cc = tn + wnw + n * 16 + r15;
        Cb[(size_t)r * N + cc] = f2bf(acc[m][n][i]);
      }
}

// ---------------- 128x128 MFMA GEMM (kept for lora2: K=256, f32 out) ----------------
__global__ __launch_bounds__(256) void gemm_bt(
    const u16* A0, const u16* A1p,
    const u16* B0, const u16* B1p,
    u16* Cb0, u16* Cb1, float* Cf0, float* Cf1,
    int N, int Kd, int out_bf16) {
  const u16* A  = blockIdx.z ? A1p : A0;
  const u16* Bm = blockIdx.z ? B1p : B0;
  u16* Cb       = blockIdx.z ? Cb1 : Cb0;
  float* Cf     = blockIdx.z ? Cf1 : Cf0;

  __shared__ __align__(16) u16 As[128 * 64];
  __shared__ __align__(16) u16 Bs[128 * 64];

  int tid = threadIdx.x;
  int tn = blockIdx.x * 128;
  int tm = blockIdx.y * 128;
  int lane = tid & 63;
  int wave = tid >> 6;
  int wm = (wave >> 1) * 64, wn = (wave & 1) * 64;
  const int r15 = lane & 15, q = lane >> 4;

  f32x4 acc[4][4] = {};

  for (int k0 = 0; k0 < Kd; k0 += 64) {
#pragma unroll
    for (int it = 0; it < 4; it++) {
      int c = it * 256 + tid;
      int row = c >> 3, c8 = c & 7;
      int scol = ((c8 ^ (row & 7)) << 3);
      gload16(A + (size_t)(tm + row) * Kd + (k0 + scol), As + c * 8);
      gload16(Bm + (size_t)(tn + row) * Kd + (k0 + scol), Bs + c * 8);
    }
    __syncthreads();
#pragma unroll
    for (int kk = 0; kk < 2; kk++) {
      short8 af[4], bfr[4];
#pragma unroll
      for (int mi = 0; mi < 4; mi++) {
        int row = wm + mi * 16 + r15;
        int kc = (kk * 4 + q) ^ (row & 7);
        af[mi] = *(const short8*)(As + row * 64 + kc * 8);
      }
#pragma unroll
      for (int ni = 0; ni < 4; ni++) {
        int row = wn + ni * 16 + r15;
        int kc = (kk * 4 + q) ^ (row & 7);
        bfr[ni] = *(const short8*)(Bs + row * 64 + kc * 8);
      }
#pragma unroll
      for (int mi = 0; mi < 4; mi++)
#pragma unroll
        for (int ni = 0; ni < 4; ni++)
          acc[mi][ni] = __builtin_amdgcn_mfma_f32_16x16x32_bf16(af[mi], bfr[ni], acc[mi][ni], 0, 0, 0);
    }
    __syncthreads();
  }
#pragma unroll
  for (int mi = 0; mi < 4; mi++)
#pragma unroll
    for (int ni = 0; ni < 4; ni++)
#pragma unroll
      for (int i = 0; i < 4; i++) {
        int r = tm + wm + mi * 16 + q * 4 + i;
        int cc = tn + wn + ni * 16 + r15;
        float v = acc[mi][ni][i];
        if (out_bf16) Cb[(size_t)r * N + cc] = f2bf(v);
        else          Cf[(size_t)r * N + cc] = v;
      }
}

// ---------------- mask/expand: a1_all/a3_all (Y-aug cols) -> zero-padded ahat ----------------
__global__ __launch_bounds__(256) void mask13_kernel(
    const u16* __restrict__ Y1, const u16* __restrict__ Y3,
    const int* __restrict__ sel, u16* __restrict__ ah1, u16* __restrict__ ah3) {
  int tk = blockIdx.x;
  int t = tk >> 1;
  int e = sel[tk] & 7;
  int c = threadIdx.x;
  bool in = (c >> 5) == e;
  ah1[(size_t)tk * 256 + c] = in ? Y1[(size_t)t * NA1 + FF + c] : (u16)0;
  ah3[(size_t)tk * 256 + c] = in ? Y3[(size_t)t * NA1 + FF + c] : (u16)0;
}

__global__ __launch_bounds__(256) void mask2_kernel(
    const u16* __restrict__ down_aug, const int* __restrict__ sel,
    u16* __restrict__ ah2) {
  int tk = blockIdx.x;
  int t = tk >> 1, k = tk & 1;
  int e = sel[tk] & 7;
  int c = threadIdx.x;
  ah2[(size_t)tk * 256 + c] =
      ((c >> 5) == e) ? down_aug[((size_t)k * TT + t) * NA2 + HH + c] : (u16)0;
}

// ---------------- fused lora1/lora3 GEMM + add-base + silu -> X2 ----------------
__global__ __launch_bounds__(256) void lora_silu_kernel(
    const u16* __restrict__ ah1, const u16* __restrict__ ah3,
    const u16* __restrict__ Bm1, const u16* __restrict__ Bm3,
    const u16* __restrict__ Y1, const u16* __restrict__ Y3,
    u16* __restrict__ X2) {
  __shared__ __align__(16) u16 Bs1[128 * 64];
  __shared__ __align__(16) u16 Bs3[128 * 64];
  int tid = threadIdx.x;
  int tn = blockIdx.x * 128;   // f tile
  int tm = blockIdx.y * 128;   // slot (tk) tile
  int lane = tid & 63, wave = tid >> 6;
  int wm = (wave >> 1) * 64, wn = (wave & 1) * 64;
  const int r15 = lane & 15, q = lane >> 4;

  f32x4 acc1[4][4] = {}, acc3[4][4] = {};

  for (int k0 = 0; k0 < 256; k0 += 64) {
#pragma unroll
    for (int it = 0; it < 4; it++) {
      int c = it * 256 + tid;
      int row = c >> 3, c8 = c & 7;
      int scol = ((c8 ^ (row & 7)) << 3);
      gload16(Bm1 + (size_t)(tn + row) * 256 + (k0 + scol), Bs1 + c * 8);
      gload16(Bm3 + (size_t)(tn + row) * 256 + (k0 + scol), Bs3 + c * 8);
    }
    __syncthreads();
#pragma unroll
    for (int kk = 0; kk < 2; kk++) {
      short8 a1f[4], a3f[4], b1f[4], b3f[4];
#pragma unroll
      for (int mi = 0; mi < 4; mi++) {
        int row = tm + wm + mi * 16 + r15;
        size_t o = (size_t)row * 256 + k0 + (kk * 4 + q) * 8;
        a1f[mi] = *(const short8*)(ah1 + o);
        a3f[mi] = *(const short8*)(ah3 + o);
      }
#pragma unroll
      for (int ni = 0; ni < 4; ni++) {
        int row = wn + ni * 16 + r15;
        int kc = (kk * 4 + q) ^ (row & 7);
        b1f[ni] = *(const short8*)(Bs1 + row * 64 + kc * 8);
        b3f[ni] = *(const short8*)(Bs3 + row * 64 + kc * 8);
      }
#pragma unroll
      for (int mi = 0; mi < 4; mi++)
#pragma unroll
        for (int ni = 0; ni < 4; ni++) {
          acc1[mi][ni] = __builtin_amdgcn_mfma_f32_16x16x32_bf16(a1f[mi], b1f[ni], acc1[mi][ni], 0, 0, 0);
          acc3[mi][ni] = __builtin_amdgcn_mfma_f32_16x16x32_bf16(a3f[mi], b3f[ni], acc3[mi][ni], 0, 0, 0);
        }
    }
    __syncthreads();
  }
#pragma unroll
  for (int mi = 0; mi < 4; mi++)
#pragma unroll
    for (int ni = 0; ni < 4; ni++)
#pragma unroll
      for (int i = 0; i < 4; i++) {
        int row = tm + wm + mi * 16 + q * 4 + i;   // tk slot
        int f = tn + wn + ni * 16 + r15;
        int t = row >> 1, k = row & 1;
        float x1 = bf2f(Y1[(size_t)t * NA1 + f]) + acc1[mi][ni][i];
        float x3 = bf2f(Y3[(size_t)t * NA1 + f]) + acc3[mi][ni][i];
        float sig = 1.f / (1.f + __expf(-x1));
        X2[((size_t)k * TT + t) * FF + f] = f2bf(x1 * sig * x3);
      }
}

// ---------------- out = sum_k rw_k * (down_k + lora2_k)  (f32 out, vectorized) ----------------
__global__ __launch_bounds__(256) void final_kernel(
    const u16* __restrict__ down_aug, const float* __restrict__ L2b,
    const float* __restrict__ rw, float* __restrict__ out) {
  int t = blockIdx.x;
  float r0 = rw[t * 2], r1 = rw[t * 2 + 1];
  int h = threadIdx.x * 8;   // 256 threads * 8 = 2048 = HH exactly
  short8 d0v = *(const short8*)(down_aug + (size_t)t * NA2 + h);
  short8 d1v = *(const short8*)(down_aug + ((size_t)TT + t) * NA2 + h);
  const float* l0p = L2b + (size_t)(t * 2) * HH + h;
  const float* l1p = L2b + (size_t)(t * 2 + 1) * HH + h;
  f32x4 l0a = *(const f32x4*)(l0p),     l0b = *(const f32x4*)(l0p + 4);
  f32x4 l1a = *(const f32x4*)(l1p),     l1b = *(const f32x4*)(l1p + 4);
  f32x4 oa, ob;
#pragma unroll
  for (int j = 0; j < 4; j++) {
    oa[j] = r0 * (bf2f((u16)d0v[j])     + l0a[j]) + r1 * (bf2f((u16)d1v[j])     + l1a[j]);
    ob[j] = r0 * (bf2f((u16)d0v[j + 4]) + l0b[j]) + r1 * (bf2f((u16)d1v[j + 4]) + l1b[j]);
  }
  float* op = out + (size_t)t * HH + h;
  *(f32x4*)(op)     = oa;
  *(f32x4*)(op + 4) = ob;
}

extern "C" void kernel_launch(void* const* d_in, const int* in_sizes, int n_in,
                              void* d_out, int out_size, void* d_ws, size_t ws_size,
                              hipStream_t stream) {
  if (n_in < 11) return;
  const float* X  = (const float*)d_in[0];
  const float* Wg = (const float*)d_in[1];
  const float* W1 = (const float*)d_in[2];
  const float* W2 = (const float*)d_in[3];
  const float* W3 = (const float*)d_in[4];
  const float* A1 = (const float*)d_in[5];
  const float* B1 = (const float*)d_in[6];
  const float* A2 = (const float*)d_in[7];
  const float* B2 = (const float*)d_in[8];
  const float* A3 = (const float*)d_in[9];
  const float* B3 = (const float*)d_in[10];
  float* out = (float*)d_out;

  char* ws = (char*)d_ws;
  size_t off = 0;
  auto take = [&](size_t bytes) -> void* {
    void* p = ws + off;
    off += (bytes + 255) & ~(size_t)255;
    return p;
  };
  u16*   Xb     = (u16*)take((size_t)TT * HH * 2);
  u16*   W1augb = (u16*)take((size_t)NA1 * HH * 2);   // rows: W1 | A1flat
  u16*   W3augb = (u16*)take((size_t)NA1 * HH * 2);   // rows: W3 | A3flat
  u16*   W2augb = (u16*)take((size_t)NA2 * FF * 2);   // rows: W2 | A2flat
  u16*   Bm1    = (u16*)take((size_t)FF * 256 * 2);
  u16*   Bm3    = (u16*)take((size_t)FF * 256 * 2);
  u16*   Bm2    = (u16*)take((size_t)HH * 256 * 2);
  u16*   Y1aug  = (u16*)take((size_t)TT * NA1 * 2);
  u16*   Y3aug  = (u16*)take((size_t)TT * NA1 * 2);
  u16*   ah1    = (u16*)take((size_t)TT * KT * 256 * 2);
  u16*   ah3    = (u16*)take((size_t)TT * KT * 256 * 2);
  u16*   ah2    = (u16*)take((size_t)TT * KT * 256 * 2);
  u16*   X2     = (u16*)take((size_t)KT * TT * FF * 2);
  int*   sel    = (int*)take((size_t)TT * KT * 4);
  float* rw     = (float*)take((size_t)TT * KT * 4);
  if (off > ws_size) return;
  // Aliases into regions that are dead by the time these are written:
  // down_aug (2*2048*2304*2 = 18.9 MB) overlays W1augb (dead after GEMM13).
  // L2b (4096*2048*4 = 33.6 MB) overlays W3augb + start of W2augb (both dead after down GEMM).
  u16*   down_aug = W1augb;
  float* L2b      = (float*)W3augb;

  // --- precompute: bf16 casts + repacks (weights are reused many times) ---
  cvt_kernel<<<1024, 256, 0, stream>>>(X,  Xb, TT * HH / 4);
  cvt_kernel<<<1024, 256, 0, stream>>>(W1, W1augb, FF * HH / 4);
  cvt_kernel<<<1024, 256, 0, stream>>>(A1, W1augb + (size_t)FF * HH, 256 * HH / 4);
  cvt_kernel<<<1024, 256, 0, stream>>>(W3, W3augb, FF * HH / 4);
  cvt_kernel<<<1024, 256, 0, stream>>>(A3, W3augb + (size_t)FF * HH, 256 * HH / 4);
  cvt_kernel<<<1024, 256, 0, stream>>>(W2, W2augb, HH * FF / 4);
  cvt_kernel<<<1024, 256, 0, stream>>>(A2, W2augb + (size_t)HH * FF, 256 * FF / 4);
  repackB_kernel<<<1024, 256, 0, stream>>>(B1, Bm1, FF);
  repackB_kernel<<<1024, 256, 0, stream>>>(B3, Bm3, FF);
  repackB_kernel<<<1024, 256, 0, stream>>>(B2, Bm2, HH);
  gating_kernel<<<TT, 64, 0, stream>>>(X, Wg, sel, rw);

  // --- Y1aug/Y3aug = Xb @ [W1|A1flat]^T, [W3|A3flat]^T  (256² 8-phase) ---
  gemm256<<<dim3(NA1 / 256, TT / 256, 2), 512, 0, stream>>>(
      Xb, Xb, W1augb, W3augb, Y1aug, Y3aug, NA1, HH);
  mask13_kernel<<<TT * KT, 256, 0, stream>>>(Y1aug, Y3aug, sel, ah1, ah3);
  // --- X2 = silu(Y1 + ah1@Bm1^T) * (Y3 + ah3@Bm3^T) ---
  lora_silu_kernel<<<dim3(FF / 128, TT * KT / 128), 256, 0, stream>>>(
      ah1, ah3, Bm1, Bm3, Y1aug, Y3aug, X2);
  // --- down_aug = X2[k] @ [W2|A2flat]^T  (256² 8-phase) ---
  gemm256<<<dim3(NA2 / 256, TT / 256, 2), 512, 0, stream>>>(
      X2, X2 + (size_t)TT * FF, W2augb, W2augb,
      down_aug, down_aug + (size_t)TT * NA2, NA2, FF);
  mask2_kernel<<<TT * KT, 256, 0, stream>>>(down_aug, sel, ah2);
  // --- L2b = ah2 @ Bm2^T ---
  gemm_bt<<<dim3(HH / 128, TT * KT / 128, 1), 256, 0, stream>>>(
      ah2, ah2, Bm2, Bm2, nullptr, nullptr, L2b, L2b, HH, 256, 0);
  final_kernel<<<TT, 256, 0, stream>>>(down_aug, L2b, rw, out);
}

// Round 3
// 701.344 us; speedup vs baseline: 1.2570x; 1.0041x over previous
//
#include <hip/hip_runtime.h>

typedef unsigned short u16;
typedef unsigned int u32;
typedef __attribute__((ext_vector_type(4))) float f32x4;
typedef __attribute__((ext_vector_type(8))) short short8;  // bf16 bits in i16 lanes

constexpr int TT = 2048;   // tokens = B*S
constexpr int HH = 2048;   // hidden
constexpr int FF = 7168;   // ffn
constexpr int RR = 32;     // lora rank
constexpr int KT = 2;      // top-k
constexpr int NA1 = FF + 256;   // 7424: W1/W3 aug N (A1flat/A3flat appended)
constexpr int NA2 = HH + 256;   // 2304: W2 aug N (A2flat appended)

__device__ __forceinline__ float bf2f(u16 v) {
  union { u32 u; float f; } w; w.u = ((u32)v) << 16; return w.f;
}
__device__ __forceinline__ u16 f2bf(float f) {
  union { float f; u32 u; } w; w.f = f;
  u32 u = w.u;
  return (u16)((u + 0x7FFFu + ((u >> 16) & 1u)) >> 16);
}

// global -> LDS direct DMA, 16 bytes/lane. LDS dest must be linear
// (wave-uniform base + lane*16); swizzle lives in the SOURCE address (rule 21).
__device__ __forceinline__ void gload16(const u16* g, u16* l) {
  __builtin_amdgcn_global_load_lds(
      (__attribute__((address_space(1))) void*)g,
      (__attribute__((address_space(3))) void*)l, 16, 0, 0);
}

// raw barrier (no vmcnt drain) + explicit waits — 8-phase schedule plumbing
__device__ __forceinline__ void bar_mem() { asm volatile("s_barrier" ::: "memory"); }
__device__ __forceinline__ void lgk0() { asm volatile("s_waitcnt lgkmcnt(0)" ::: "memory"); }
template <int N>
__device__ __forceinline__ void vmw() { asm volatile("s_waitcnt vmcnt(%0)" :: "n"(N) : "memory"); }

// ---------------- f32 -> bf16 conversion (grid-stride, float4) ----------------
__global__ __launch_bounds__(256) void cvt_kernel(
    const float* __restrict__ src, u16* __restrict__ dst, int n4) {
  int stride = gridDim.x * 256;
  for (int i = blockIdx.x * 256 + threadIdx.x; i < n4; i += stride) {
    float4 v = ((const float4*)src)[i];
    ushort4 o;
    o.x = f2bf(v.x); o.y = f2bf(v.y); o.z = f2bf(v.z); o.w = f2bf(v.w);
    ((ushort4*)dst)[i] = o;
  }
}

// ---------------- repack B [E, Fdim, R] f32 -> Bm [Fdim, E*R] bf16 ----------------
__global__ __launch_bounds__(256) void repackB_kernel(
    const float* __restrict__ B, u16* __restrict__ Bm, int Fdim) {
  int n = Fdim * 256;
  int stride = gridDim.x * 256;
  for (int i = blockIdx.x * 256 + threadIdx.x; i < n; i += stride) {
    int f = i >> 8, c = i & 255, e = c >> 5, r = c & 31;
    Bm[i] = f2bf(B[((size_t)e * Fdim + f) * RR + r]);
  }
}

// ---------------- gating: logits -> top2 -> weights (f32 exact) ----------------
__global__ __launch_bounds__(64) void gating_kernel(
    const float* __restrict__ X, const float* __restrict__ Wg,
    int* __restrict__ sel, float* __restrict__ rw) {
  int t = blockIdx.x;
  int lane = threadIdx.x;
  const float* x = X + (size_t)t * HH;
  float acc[8] = {};
  for (int h = lane; h < HH; h += 64) {
    float xv = x[h];
#pragma unroll
    for (int e = 0; e < 8; e++) acc[e] += xv * Wg[e * HH + h];
  }
#pragma unroll
  for (int e = 0; e < 8; e++)
    for (int off = 32; off; off >>= 1) acc[e] += __shfl_down(acc[e], off);
  if (lane == 0) {
    int b0 = 0; float l0 = acc[0];
    for (int e = 1; e < 8; e++) if (acc[e] > l0) { l0 = acc[e]; b0 = e; }
    int b1 = -1; float l1 = 0.f;
    for (int e = 0; e < 8; e++) {
      if (e == b0) continue;
      if (b1 < 0 || acc[e] > l1) { l1 = acc[e]; b1 = e; }
    }
    float p = 1.f / (1.f + __expf(l1 - l0));
    sel[t * 2 + 0] = b0; sel[t * 2 + 1] = b1;
    rw[t * 2 + 0] = p;   rw[t * 2 + 1] = 1.f - p;
  }
}

// ================= 256x256 8-phase MFMA GEMM (T1+T2+T3+T4+T5) =================
// C[M,N] = A[M,K] * Bm[N,K]^T, bf16 in/out. 8 waves (2M x 4N), per-wave 128x64.
// LDS 160 KiB: A triple-buffered + B double-buffered (256x64 tiles each),
// XOR-swizzled via pre-swizzled gload source. Prefetch depth: 4 half-tiles in
// flight, vmcnt(8) at phases 4/8 only — covers HBM-miss latency (~900 cy).
// Staging map (iter 'it' handles tiles t0=2it [Acur,B0b], t1=2it+1 [Anext,B1b]):
//   P1/P2: t2.A -> Afree   P3/P4: t2.B -> B0b  [vmw<8>]
//   P5/P6: t3.A -> Acur    P7/P8: t3.B -> B1b  [vmw<8>]
// Liveness: Afree unused; B0b last read P2; Acur last read P3; B1b last read P6.
__device__ __forceinline__ void stageH(const u16* g, int stride, int row0, int k0,
                                       u16* l) {
  const int tid = threadIdx.x;
#pragma unroll
  for (int j = 0; j < 2; ++j) {
    int c = (j << 9) + tid;            // 0..1023 -> 128 rows x 64 cols
    int row = c >> 3, c8 = c & 7;
    int sc = ((c8 ^ (row & 7)) << 3);  // pre-swizzled source column
    gload16(g + (size_t)(row0 + row) * stride + (k0 + sc), l + c * 8);
  }
}

#define RD_A(buf, mo)                                                         \
  _Pragma("unroll") for (int j = 0; j < 4; ++j)                               \
  _Pragma("unroll") for (int ks = 0; ks < 2; ++ks) {                          \
    int row = wmw + (mo + j) * 16 + r15;                                      \
    a[j * 2 + ks] = *(const short8*)((buf) + row * 64 +                       \
                                     (((ks * 4 + q) ^ (row & 7)) << 3));      \
  }
#define RD_B(buf, reg, no)                                                    \
  _Pragma("unroll") for (int n = 0; n < 2; ++n)                               \
  _Pragma("unroll") for (int ks = 0; ks < 2; ++ks) {                          \
    int row = wnw + (no + n) * 16 + r15;                                      \
    reg[n * 2 + ks] = *(const short8*)((buf) + row * 64 +                     \
                                       (((ks * 4 + q) ^ (row & 7)) << 3));    \
  }
#define MMQ(mo, reg, no)                                                      \
  _Pragma("unroll") for (int m = 0; m < 4; ++m)                               \
  _Pragma("unroll") for (int n = 0; n < 2; ++n)                               \
  _Pragma("unroll") for (int ks = 0; ks < 2; ++ks)                            \
    acc[mo + m][no + n] = __builtin_amdgcn_mfma_f32_16x16x32_bf16(            \
        a[m * 2 + ks], reg[n * 2 + ks], acc[mo + m][no + n], 0, 0, 0);

__global__ __launch_bounds__(512, 2) void gemm256(
    const u16* A0, const u16* A1p, const u16* B0, const u16* B1p,
    u16* Cb0, u16* Cb1, int N, int Kd) {
  const u16* A  = blockIdx.z ? A1p : A0;
  const u16* Bm = blockIdx.z ? B1p : B0;
  u16* Cb       = blockIdx.z ? Cb1 : Cb0;

  __shared__ __align__(16) u16 S[81920];  // 160 KiB: A x3 | B x2 (256x64 each)
  u16* Acur  = S;
  u16* Anext = S + 16384;
  u16* Afree = S + 32768;
  u16* B0b   = S + 49152;
  u16* B1b   = S + 65536;

  // XCD-aware bijective swizzle (nwg % 8 == 0 for both call sites), N-chunked.
  const int gx = gridDim.x, gy = gridDim.y;
  const int nwg = gx * gy;
  const int orig = blockIdx.y * gx + blockIdx.x;
  const int wg = (orig & 7) * (nwg >> 3) + (orig >> 3);
  const int tn = (wg / gy) * 256;
  const int tm = (wg % gy) * 256;

  const int tid = threadIdx.x;
  const int lane = tid & 63, wave = tid >> 6;
  const int wmw = (wave >> 2) * 128;   // wave M offset (2 groups)
  const int wnw = (wave & 3) * 64;     // wave N offset (4 groups)
  const int r15 = lane & 15, q = lane >> 4;

  f32x4 acc[8][4] = {};
  short8 a[8], bl[4], bh[4];

  const int nIter = Kd >> 7;   // pairs of 64-wide K-tiles

  // prologue: t0 (A+B) then t1 (A+B); oldest 8 = t0 -> vmw<8> drains exactly t0
  stageH(A,  Kd, tm,       0,  Acur);
  stageH(A,  Kd, tm + 128, 0,  Acur + 8192);
  stageH(Bm, Kd, tn,       0,  B0b);
  stageH(Bm, Kd, tn + 128, 0,  B0b + 8192);
  stageH(A,  Kd, tm,       64, Anext);
  stageH(A,  Kd, tm + 128, 64, Anext + 8192);
  stageH(Bm, Kd, tn,       64, B1b);
  stageH(Bm, Kd, tn + 128, 64, B1b + 8192);
  vmw<8>();
  bar_mem();

  for (int it = 0; it < nIter; ++it) {
    const bool st = (it + 1 < nIter);
    const int k2 = (2 * it + 2) << 6;
    const int k3 = (2 * it + 3) << 6;

    // ---- K-tile t0 (Acur, B0b) ----
    // P1: Q1 (M-lo x N-lo)
    RD_A(Acur, 0) RD_B(B0b, bl, 0)
    if (st) stageH(A, Kd, tm, k2, Afree);
    bar_mem(); lgk0();
    __builtin_amdgcn_s_setprio(1); MMQ(0, bl, 0) __builtin_amdgcn_s_setprio(0);
    bar_mem();
    // P2: Q2 (M-lo x N-hi)
    RD_B(B0b, bh, 2)
    if (st) stageH(A, Kd, tm + 128, k2, Afree + 8192);
    bar_mem(); lgk0();
    __builtin_amdgcn_s_setprio(1); MMQ(0, bh, 2) __builtin_amdgcn_s_setprio(0);
    bar_mem();
    // P3: Q3 (M-hi x N-hi)
    RD_A(Acur, 4)
    if (st) stageH(Bm, Kd, tn, k2, B0b);
    bar_mem(); lgk0();
    __builtin_amdgcn_s_setprio(1); MMQ(4, bh, 2) __builtin_amdgcn_s_setprio(0);
    bar_mem();
    // P4: Q4 (M-hi x N-lo); counted vmcnt — drains t1.A/t1.B (needed P5)
    if (st) stageH(Bm, Kd, tn + 128, k2, B0b + 8192);
    bar_mem();
    __builtin_amdgcn_s_setprio(1); MMQ(4, bl, 0) __builtin_amdgcn_s_setprio(0);
    if (st) vmw<8>(); else vmw<0>();
    bar_mem();

    // ---- K-tile t1 (Anext, B1b) ----
    // P5
    RD_A(Anext, 0) RD_B(B1b, bl, 0)
    if (st) stageH(A, Kd, tm, k3, Acur);
    bar_mem(); lgk0();
    __builtin_amdgcn_s_setprio(1); MMQ(0, bl, 0) __builtin_amdgcn_s_setprio(0);
    bar_mem();
    // P6
    RD_B(B1b, bh, 2)
    if (st) stageH(A, Kd, tm + 128, k3, Acur + 8192);
    bar_mem(); lgk0();
    __builtin_amdgcn_s_setprio(1); MMQ(0, bh, 2) __builtin_amdgcn_s_setprio(0);
    bar_mem();
    // P7
    RD_A(Anext, 4)
    if (st) stageH(Bm, Kd, tn, k3, B1b);
    bar_mem(); lgk0();
    __builtin_amdgcn_s_setprio(1); MMQ(4, bh, 2) __builtin_amdgcn_s_setprio(0);
    bar_mem();
    // P8: counted vmcnt — drains t2.A/t2.B (needed next-P1)
    if (st) stageH(Bm, Kd, tn + 128, k3, B1b + 8192);
    bar_mem();
    __builtin_amdgcn_s_setprio(1); MMQ(4, bl, 0) __builtin_amdgcn_s_setprio(0);
    if (st) vmw<8>();
    bar_mem();

    // rotate A buffers: next iter's t0 = old Afree, t1 = old Acur
    u16* tmp = Afree; Afree = Anext; Anext = Acur; Acur = tmp;
  }

#pragma unroll
  for (int m = 0; m < 8; ++m)
#pragma unroll
    for (int n = 0; n < 4; ++n)
#pragma unroll
      for (int i = 0; i < 4; ++i) {
        int r = tm + wmw + m * 16 + q * 4 + i;
        int cc = tn + wnw + n * 16 + r15;
        Cb[(size_t)r * N + cc] = f2bf(acc[m][n][i]);
      }
}

// ---------------- 128x128 MFMA GEMM (kept for lora2: K=256, f32 out) ----------------
__global__ __launch_bounds__(256) void gemm_bt(
    const u16* A0, const u16* A1p,
    const u16* B0, const u16* B1p,
    u16* Cb0, u16* Cb1, float* Cf0, float* Cf1,
    int N, int Kd, int out_bf16) {
  const u16* A  = blockIdx.z ? A1p : A0;
  const u16* Bm = blockIdx.z ? B1p : B0;
  u16* Cb       = blockIdx.z ? Cb1 : Cb0;
  float* Cf     = blockIdx.z ? Cf1 : Cf0;

  __shared__ __align__(16) u16 As[128 * 64];
  __shared__ __align__(16) u16 Bs[128 * 64];

  int tid = threadIdx.x;
  int tn = blockIdx.x * 128;
  int tm = blockIdx.y * 128;
  int lane = tid & 63;
  int wave = tid >> 6;
  int wm = (wave >> 1) * 64, wn = (wave & 1) * 64;
  const int r15 = lane & 15, q = lane >> 4;

  f32x4 acc[4][4] = {};

  for (int k0 = 0; k0 < Kd; k0 += 64) {
#pragma unroll
    for (int it = 0; it < 4; it++) {
      int c = it * 256 + tid;
      int row = c >> 3, c8 = c & 7;
      int scol = ((c8 ^ (row & 7)) << 3);
      gload16(A + (size_t)(tm + row) * Kd + (k0 + scol), As + c * 8);
      gload16(Bm + (size_t)(tn + row) * Kd + (k0 + scol), Bs + c * 8);
    }
    __syncthreads();
#pragma unroll
    for (int kk = 0; kk < 2; kk++) {
      short8 af[4], bfr[4];
#pragma unroll
      for (int mi = 0; mi < 4; mi++) {
        int row = wm + mi * 16 + r15;
        int kc = (kk * 4 + q) ^ (row & 7);
        af[mi] = *(const short8*)(As + row * 64 + kc * 8);
      }
#pragma unroll
      for (int ni = 0; ni < 4; ni++) {
        int row = wn + ni * 16 + r15;
        int kc = (kk * 4 + q) ^ (row & 7);
        bfr[ni] = *(const short8*)(Bs + row * 64 + kc * 8);
      }
#pragma unroll
      for (int mi = 0; mi < 4; mi++)
#pragma unroll
        for (int ni = 0; ni < 4; ni++)
          acc[mi][ni] = __builtin_amdgcn_mfma_f32_16x16x32_bf16(af[mi], bfr[ni], acc[mi][ni], 0, 0, 0);
    }
    __syncthreads();
  }
#pragma unroll
  for (int mi = 0; mi < 4; mi++)
#pragma unroll
    for (int ni = 0; ni < 4; ni++)
#pragma unroll
      for (int i = 0; i < 4; i++) {
        int r = tm + wm + mi * 16 + q * 4 + i;
        int cc = tn + wn + ni * 16 + r15;
        float v = acc[mi][ni][i];
        if (out_bf16) Cb[(size_t)r * N + cc] = f2bf(v);
        else          Cf[(size_t)r * N + cc] = v;
      }
}

// ---------------- mask/expand: a1_all/a3_all (Y-aug cols) -> zero-padded ahat ----------------
__global__ __launch_bounds__(256) void mask13_kernel(
    const u16* __restrict__ Y1, const u16* __restrict__ Y3,
    const int* __restrict__ sel, u16* __restrict__ ah1, u16* __restrict__ ah3) {
  int tk = blockIdx.x;
  int t = tk >> 1;
  int e = sel[tk] & 7;
  int c = threadIdx.x;
  bool in = (c >> 5) == e;
  ah1[(size_t)tk * 256 + c] = in ? Y1[(size_t)t * NA1 + FF + c] : (u16)0;
  ah3[(size_t)tk * 256 + c] = in ? Y3[(size_t)t * NA1 + FF + c] : (u16)0;
}

__global__ __launch_bounds__(256) void mask2_kernel(
    const u16* __restrict__ down_aug, const int* __restrict__ sel,
    u16* __restrict__ ah2) {
  int tk = blockIdx.x;
  int t = tk >> 1, k = tk & 1;
  int e = sel[tk] & 7;
  int c = threadIdx.x;
  ah2[(size_t)tk * 256 + c] =
      ((c >> 5) == e) ? down_aug[((size_t)k * TT + t) * NA2 + HH + c] : (u16)0;
}

// ---------------- fused lora1/lora3 GEMM + add-base + silu -> X2 ----------------
__global__ __launch_bounds__(256) void lora_silu_kernel(
    const u16* __restrict__ ah1, const u16* __restrict__ ah3,
    const u16* __restrict__ Bm1, const u16* __restrict__ Bm3,
    const u16* __restrict__ Y1, const u16* __restrict__ Y3,
    u16* __restrict__ X2) {
  __shared__ __align__(16) u16 Bs1[128 * 64];
  __shared__ __align__(16) u16 Bs3[128 * 64];
  int tid = threadIdx.x;
  int tn = blockIdx.x * 128;   // f tile
  int tm = blockIdx.y * 128;   // slot (tk) tile
  int lane = tid & 63, wave = tid >> 6;
  int wm = (wave >> 1) * 64, wn = (wave & 1) * 64;
  const int r15 = lane & 15, q = lane >> 4;

  f32x4 acc1[4][4] = {}, acc3[4][4] = {};

  for (int k0 = 0; k0 < 256; k0 += 64) {
#pragma unroll
    for (int it = 0; it < 4; it++) {
      int c = it * 256 + tid;
      int row = c >> 3, c8 = c & 7;
      int scol = ((c8 ^ (row & 7)) << 3);
      gload16(Bm1 + (size_t)(tn + row) * 256 + (k0 + scol), Bs1 + c * 8);
      gload16(Bm3 + (size_t)(tn + row) * 256 + (k0 + scol), Bs3 + c * 8);
    }
    __syncthreads();
#pragma unroll
    for (int kk = 0; kk < 2; kk++) {
      short8 a1f[4], a3f[4], b1f[4], b3f[4];
#pragma unroll
      for (int mi = 0; mi < 4; mi++) {
        int row = tm + wm + mi * 16 + r15;
        size_t o = (size_t)row * 256 + k0 + (kk * 4 + q) * 8;
        a1f[mi] = *(const short8*)(ah1 + o);
        a3f[mi] = *(const short8*)(ah3 + o);
      }
#pragma unroll
      for (int ni = 0; ni < 4; ni++) {
        int row = wn + ni * 16 + r15;
        int kc = (kk * 4 + q) ^ (row & 7);
        b1f[ni] = *(const short8*)(Bs1 + row * 64 + kc * 8);
        b3f[ni] = *(const short8*)(Bs3 + row * 64 + kc * 8);
      }
#pragma unroll
      for (int mi = 0; mi < 4; mi++)
#pragma unroll
        for (int ni = 0; ni < 4; ni++) {
          acc1[mi][ni] = __builtin_amdgcn_mfma_f32_16x16x32_bf16(a1f[mi], b1f[ni], acc1[mi][ni], 0, 0, 0);
          acc3[mi][ni] = __builtin_amdgcn_mfma_f32_16x16x32_bf16(a3f[mi], b3f[ni], acc3[mi][ni], 0, 0, 0);
        }
    }
    __syncthreads();
  }
#pragma unroll
  for (int mi = 0; mi < 4; mi++)
#pragma unroll
    for (int ni = 0; ni < 4; ni++)
#pragma unroll
      for (int i = 0; i < 4; i++) {
        int row = tm + wm + mi * 16 + q * 4 + i;   // tk slot
        int f = tn + wn + ni * 16 + r15;
        int t = row >> 1, k = row & 1;
        float x1 = bf2f(Y1[(size_t)t * NA1 + f]) + acc1[mi][ni][i];
        float x3 = bf2f(Y3[(size_t)t * NA1 + f]) + acc3[mi][ni][i];
        float sig = 1.f / (1.f + __expf(-x1));
        X2[((size_t)k * TT + t) * FF + f] = f2bf(x1 * sig * x3);
      }
}

// ---------------- out = sum_k rw_k * (down_k + lora2_k)  (f32 out, vectorized) ----------------
__global__ __launch_bounds__(256) void final_kernel(
    const u16* __restrict__ down_aug, const float* __restrict__ L2b,
    const float* __restrict__ rw, float* __restrict__ out) {
  int t = blockIdx.x;
  float r0 = rw[t * 2], r1 = rw[t * 2 + 1];
  int h = threadIdx.x * 8;   // 256 threads * 8 = 2048 = HH exactly
  short8 d0v = *(const short8*)(down_aug + (size_t)t * NA2 + h);
  short8 d1v = *(const short8*)(down_aug + ((size_t)TT + t) * NA2 + h);
  const float* l0p = L2b + (size_t)(t * 2) * HH + h;
  const float* l1p = L2b + (size_t)(t * 2 + 1) * HH + h;
  f32x4 l0a = *(const f32x4*)(l0p),     l0b = *(const f32x4*)(l0p + 4);
  f32x4 l1a = *(const f32x4*)(l1p),     l1b = *(const f32x4*)(l1p + 4);
  f32x4 oa, ob;
#pragma unroll
  for (int j = 0; j < 4; j++) {
    oa[j] = r0 * (bf2f((u16)d0v[j])     + l0a[j]) + r1 * (bf2f((u16)d1v[j])     + l1a[j]);
    ob[j] = r0 * (bf2f((u16)d0v[j + 4]) + l0b[j]) + r1 * (bf2f((u16)d1v[j + 4]) + l1b[j]);
  }
  float* op = out + (size_t)t * HH + h;
  *(f32x4*)(op)     = oa;
  *(f32x4*)(op + 4) = ob;
}

extern "C" void kernel_launch(void* const* d_in, const int* in_sizes, int n_in,
                              void* d_out, int out_size, void* d_ws, size_t ws_size,
                              hipStream_t stream) {
  if (n_in < 11) return;
  const float* X  = (const float*)d_in[0];
  const float* Wg = (const float*)d_in[1];
  const float* W1 = (const float*)d_in[2];
  const float* W2 = (const float*)d_in[3];
  const float* W3 = (const float*)d_in[4];
  const float* A1 = (const float*)d_in[5];
  const float* B1 = (const float*)d_in[6];
  const float* A2 = (const float*)d_in[7];
  const float* B2 = (const float*)d_in[8];
  const float* A3 = (const float*)d_in[9];
  const float* B3 = (const float*)d_in[10];
  float* out = (float*)d_out;

  char* ws = (char*)d_ws;
  size_t off = 0;
  auto take = [&](size_t bytes) -> void* {
    void* p = ws + off;
    off += (bytes + 255) & ~(size_t)255;
    return p;
  };
  u16*   Xb     = (u16*)take((size_t)TT * HH * 2);
  u16*   W1augb = (u16*)take((size_t)NA1 * HH * 2);   // rows: W1 | A1flat
  u16*   W3augb = (u16*)take((size_t)NA1 * HH * 2);   // rows: W3 | A3flat
  u16*   W2augb = (u16*)take((size_t)NA2 * FF * 2);   // rows: W2 | A2flat
  u16*   Bm1    = (u16*)take((size_t)FF * 256 * 2);
  u16*   Bm3    = (u16*)take((size_t)FF * 256 * 2);
  u16*   Bm2    = (u16*)take((size_t)HH * 256 * 2);
  u16*   Y1aug  = (u16*)take((size_t)TT * NA1 * 2);
  u16*   Y3aug  = (u16*)take((size_t)TT * NA1 * 2);
  u16*   ah1    = (u16*)take((size_t)TT * KT * 256 * 2);
  u16*   ah3    = (u16*)take((size_t)TT * KT * 256 * 2);
  u16*   ah2    = (u16*)take((size_t)TT * KT * 256 * 2);
  u16*   X2     = (u16*)take((size_t)KT * TT * FF * 2);
  int*   sel    = (int*)take((size_t)TT * KT * 4);
  float* rw     = (float*)take((size_t)TT * KT * 4);
  if (off > ws_size) return;
  // Aliases into regions that are dead by the time these are written:
  // down_aug (2*2048*2304*2 = 18.9 MB) overlays W1augb (dead after GEMM13).
  // L2b (4096*2048*4 = 33.6 MB) overlays W3augb + start of W2augb (both dead after down GEMM).
  u16*   down_aug = W1augb;
  float* L2b      = (float*)W3augb;

  // --- precompute: bf16 casts + repacks (weights are reused many times) ---
  cvt_kernel<<<1024, 256, 0, stream>>>(X,  Xb, TT * HH / 4);
  cvt_kernel<<<1024, 256, 0, stream>>>(W1, W1augb, FF * HH / 4);
  cvt_kernel<<<1024, 256, 0, stream>>>(A1, W1augb + (size_t)FF * HH, 256 * HH / 4);
  cvt_kernel<<<1024, 256, 0, stream>>>(W3, W3augb, FF * HH / 4);
  cvt_kernel<<<1024, 256, 0, stream>>>(A3, W3augb + (size_t)FF * HH, 256 * HH / 4);
  cvt_kernel<<<1024, 256, 0, stream>>>(W2, W2augb, HH * FF / 4);
  cvt_kernel<<<1024, 256, 0, stream>>>(A2, W2augb + (size_t)HH * FF, 256 * FF / 4);
  repackB_kernel<<<1024, 256, 0, stream>>>(B1, Bm1, FF);
  repackB_kernel<<<1024, 256, 0, stream>>>(B3, Bm3, FF);
  repackB_kernel<<<1024, 256, 0, stream>>>(B2, Bm2, HH);
  gating_kernel<<<TT, 64, 0, stream>>>(X, Wg, sel, rw);

  // --- Y1aug/Y3aug = Xb @ [W1|A1flat]^T, [W3|A3flat]^T  (256² 8-phase) ---
  gemm256<<<dim3(NA1 / 256, TT / 256, 2), 512, 0, stream>>>(
      Xb, Xb, W1augb, W3augb, Y1aug, Y3aug, NA1, HH);
  mask13_kernel<<<TT * KT, 256, 0, stream>>>(Y1aug, Y3aug, sel, ah1, ah3);
  // --- X2 = silu(Y1 + ah1@Bm1^T) * (Y3 + ah3@Bm3^T) ---
  lora_silu_kernel<<<dim3(FF / 128, TT * KT / 128), 256, 0, stream>>>(
      ah1, ah3, Bm1, Bm3, Y1aug, Y3aug, X2);
  // --- down_aug = X2[k] @ [W2|A2flat]^T  (256² 8-phase) ---
  gemm256<<<dim3(NA2 / 256, TT / 256, 2), 512, 0, stream>>>(
      X2, X2 + (size_t)TT * FF, W2augb, W2augb,
      down_aug, down_aug + (size_t)TT * NA2, NA2, FF);
  mask2_kernel<<<TT * KT, 256, 0, stream>>>(down_aug, sel, ah2);
  // --- L2b = ah2 @ Bm2^T ---
  gemm_bt<<<dim3(HH / 128, TT * KT / 128, 1), 256, 0, stream>>>(
      ah2, ah2, Bm2, Bm2, nullptr, nullptr, L2b, L2b, HH, 256, 0);
  final_kernel<<<TT, 256, 0, stream>>>(down_aug, L2b, rw, out);
}